// Round 3
// baseline (73559.027 us; speedup 1.0000x reference)
//
#include <hip/hip_runtime.h>
#include <cmath>

constexpr int NB = 128;     // batch
constexpr int NS = 384;     // seq len
constexpr int NH = 384;     // hidden = input dim

typedef __attribute__((ext_vector_type(2))) float f32x2;

__device__ __forceinline__ double clampd(double x, double lo, double hi){ return fmin(fmax(x,lo),hi); }
__device__ __forceinline__ double artanh_(double x){ return atanh(clampd(x, -1.0 + 1e-7, 1.0 - 1e-7)); }
__device__ __forceinline__ double normclip(double s){ return sqrt(fmax(s, 1e-15)); }
__device__ __forceinline__ double wredsumd(double v){
  #pragma unroll
  for (int off = 32; off; off >>= 1) v += __shfl_xor(v, off, 64);
  return v;
}

// ---------------- zero ----------------
__global__ void kzerod(double* p, int n){
  int i = blockIdx.x * 256 + threadIdx.x;
  if (i < n) p[i] = 0.0;
}

// ---------------- weight pack: WTP[c][j], 392 rows (8 pad rows for prefetch over-read) ----------------
// j<1536: gate W (4 gates x 384); [1536,1920): W_d; [2048,3584) (NW=4096 only): U gates; else 0.
__global__ void kprepW(const float* __restrict__ W_all, const float* __restrict__ W_d,
                       const float* __restrict__ U_all, float* __restrict__ WTP, int NW)
{
  int i = blockIdx.x * 256 + threadIdx.x;
  int total = 392 * NW;
  if (i >= total) return;
  int c = i / NW, j = i % NW;
  float v = 0.f;
  if (c < 384){
    if (j < 1536){ int g = j / 384, r = j % 384; v = W_all[r * 1536 + g * 384 + c]; }
    else if (j < 1920){ int r = j - 1536; v = W_d[r * 384 + c]; }
    else if (NW == 4096 && j >= 2048 && j < 3584){
      int jj = j - 2048; int g = jj / 384, r = jj % 384; v = U_all[(g * 384 + r) * 384 + c];
    }
  }
  WTP[i] = v;
}

// UT[c][jj] = U_g[r][c], stride 1536 (for the Qp precompute GEMM)
__global__ void kprepU(const float* __restrict__ U_all, float* __restrict__ UT)
{
  int i = blockIdx.x * 256 + threadIdx.x;
  if (i >= 384 * 1536) return;
  int c = i / 1536, jj = i % 1536;
  int g = jj / 384, r = jj % 384;
  UT[i] = U_all[(g * 384 + r) * 384 + c];
}

// ---------------- xn precompute: XND[b*NS+t] = {xn, artanh(xn)} ----------------
__global__ void kxn(const float* __restrict__ xin, double* __restrict__ XND)
{
  int w = (blockIdx.x * 256 + threadIdx.x) >> 6;
  int ln = threadIdx.x & 63;
  int nw = (gridDim.x * 256) >> 6;
  for (int idx = w; idx < NB * NS; idx += nw){
    double s = 0;
    #pragma unroll
    for (int i = 0; i < 6; ++i){
      float v = xin[(size_t)idx * NH + ln + 64 * i];
      s += (double)v * v;
    }
    s = wredsumd(s);
    if (ln == 0){
      double xn = normclip(s);
      XND[idx * 2] = xn;
      XND[idx * 2 + 1] = artanh_(xn);
    }
  }
}

// ---------------- one-time Q GEMM: Qp[bs][jj] = sum_c X[bs][c] * UT[c][jj] ----------------
__global__ __launch_bounds__(256) void kqgemm2(const float* __restrict__ X,
    const float* __restrict__ Bw, float* __restrict__ Q)
{
  int j0 = blockIdx.x * 64, i0 = blockIdx.y * 64;
  __shared__ __align__(16) float As[32][68];
  __shared__ __align__(16) float Bs[32][64];
  int tid = threadIdx.x;
  int tn = tid & 15, tm = tid >> 4;
  int slm = tid >> 2;
  int slc = (tid & 3) * 8;
  int blk = tid >> 3;
  int bln = (tid & 7) * 8;
  double accd[4][4] = {{0.0}};
  const float* arow = X + (size_t)(i0 + slm) * NH;
  for (int c0 = 0; c0 < NH; c0 += 32){
    float4 a4 = *(const float4*)(arow + c0 + slc);
    float4 a4b = *(const float4*)(arow + c0 + slc + 4);
    As[slc+0][slm] = a4.x;  As[slc+1][slm] = a4.y;
    As[slc+2][slm] = a4.z;  As[slc+3][slm] = a4.w;
    As[slc+4][slm] = a4b.x; As[slc+5][slm] = a4b.y;
    As[slc+6][slm] = a4b.z; As[slc+7][slm] = a4b.w;
    const float* bp = Bw + (size_t)(c0 + blk) * 1536 + j0 + bln;
    float4 b4a = *(const float4*)bp;
    float4 b4b = *(const float4*)(bp + 4);
    *(float4*)&Bs[blk][bln] = b4a;
    *(float4*)&Bs[blk][bln+4] = b4b;
    __syncthreads();
    float acc[4][4] = {{0.f}};
    #pragma unroll 8
    for (int c = 0; c < 32; ++c){
      float4 av = *(const float4*)&As[c][tm*4];
      float4 bv = *(const float4*)&Bs[c][tn*4];
      float a[4] = {av.x, av.y, av.z, av.w};
      float bb[4] = {bv.x, bv.y, bv.z, bv.w};
      #pragma unroll
      for (int mm = 0; mm < 4; ++mm)
        #pragma unroll
        for (int jj = 0; jj < 4; ++jj)
          acc[mm][jj] += a[mm] * bb[jj];
    }
    __syncthreads();
    #pragma unroll
    for (int mm = 0; mm < 4; ++mm)
      #pragma unroll
      for (int jj = 0; jj < 4; ++jj) accd[mm][jj] += (double)acc[mm][jj];
  }
  #pragma unroll
  for (int mm = 0; mm < 4; ++mm){
    float4 o; o.x = (float)accd[mm][0]; o.y = (float)accd[mm][1];
    o.z = (float)accd[mm][2]; o.w = (float)accd[mm][3];
    *(float4*)(Q + (size_t)(i0 + tm*4 + mm) * 1536 + j0 + tn*4) = o;
  }
}

// ---------------- gate chain (identical math to the verified knl) ----------------
__device__ __forceinline__ void gate_chain(const float* __restrict__ pg, const float* __restrict__ qg,
    double hn, double art_hn, double xn, double art_xn, float* __restrict__ out)
{
  double s_p = 0, s_q = 0;
  #pragma unroll
  for (int i = 0; i < 6; ++i){ s_p += (double)pg[i] * pg[i]; s_q += (double)qg[i] * qg[i]; }
  double pn = normclip(wredsumd(s_p));
  double qn = normclip(wredsumd(s_q));
  float saf = (float)(tanh(pn / hn * art_hn) / pn);
  float sbf = (float)(tanh(qn / xn * art_xn) / qn);
  float a6[6], b6[6]; double sx2 = 0, sy2 = 0, sxy = 0;
  #pragma unroll
  for (int i = 0; i < 6; ++i){
    a6[i] = saf * pg[i]; b6[i] = sbf * qg[i];
    sx2 += (double)a6[i] * a6[i]; sy2 += (double)b6[i] * b6[i]; sxy += (double)a6[i] * b6[i];
  }
  sx2 = wredsumd(sx2); sy2 = wredsumd(sy2); sxy = wredsumd(sxy);
  double dd = fmax(1.0 + 2.0 * sxy + sx2 * sy2, 1e-15);
  float fX = (float)((1.0 + 2.0 * sxy + sy2) / dd);
  float fY = (float)((1.0 - sx2) / dd);
  float m6[6]; double smm = 0;
  #pragma unroll
  for (int i = 0; i < 6; ++i){ m6[i] = fX * a6[i] + fY * b6[i]; smm += (double)m6[i] * m6[i]; }
  double nm = normclip(wredsumd(smm));
  float slf = (float)(artanh_(nm) / nm);
  #pragma unroll
  for (int i = 0; i < 6; ++i) out[i] = 1.f / (1.f + expf(-slf * m6[i]));
}

// ================= row-local fused recurrence: NO inter-block sync =================
// 64 blocks x 512 threads. Block owns rows 2*bid, 2*bid+1 (row-group = 256 threads, 4 waves).
// GEMM: Z[row][j] = sum_c A(c)*WTP[c][j], A in {h, cc, x, 0} selected per column range.
// NL: w0 c-path+combine, w1 gates f,i, w2 gate o(+ctx), w3 gate ct.
template<int NW, int QPRE>
__global__ __launch_bounds__(512, 1) void krow(
    const float* __restrict__ WTP, const float* __restrict__ xin,
    const float* __restrict__ tst, const double* __restrict__ XND,
    const float* __restrict__ Qp, float* __restrict__ ctx, float* __restrict__ HsOut)
{
  constexpr int NF4 = NW / 1024;        // float4 per thread per c: 2 or 4
  constexpr int D = (QPRE ? 4 : 2);     // prefetch depth
  const int tid = threadIdx.x;
  const int grp = tid >> 8;             // row-group 0/1
  const int t256 = tid & 255;
  const int wv = t256 >> 6;             // wave within group
  const int ln = tid & 63;
  const int b = (blockIdx.x << 1) | grp;

  __shared__ __align__(16) float Zrow[2][NW];
  __shared__ f32x2 ALd[2][384][5];      // slots: 0=h, 1=cc, 2=x, 3=zero (5 pads banks)
  __shared__ float g384[2][4][384];
  __shared__ double sc[2][2];           // {hn, cc2}

  // init state
  for (int i = tid; i < 2 * 384 * 5; i += 512) ((f32x2*)ALd)[i] = f32x2{0.f, 0.f};
  if (tid < 2){ sc[tid][0] = normclip(0.0); sc[tid][1] = 0.0; }
  __syncthreads();
  if (!QPRE){
    for (int i = t256; i < 384; i += 256){
      float xv = xin[(size_t)b * NS * NH + i];
      ALd[grp][i][2] = f32x2{xv, xv};
    }
    __syncthreads();
  }

  const int col0 = t256 * (NF4 * 4);
  int sel;
  if (col0 < 1536) sel = 0;
  else if (col0 < 1920) sel = 1;
  else if (QPRE) sel = 3;
  else if (col0 < 2048) sel = 3;
  else if (col0 < 3584) sel = 2;
  else sel = 3;

  float qreg[12];
  float xr[6];

  for (int t = 0; t < NS; ++t){
    // ---- prefetches (latency hidden under GEMM) ----
    double ts = 0.0, xn = 0.0, art_xn = 0.0;
    if (wv == 0) ts = (double)tst[b * NS + t];
    else { xn = XND[(b * NS + t) * 2]; art_xn = XND[(b * NS + t) * 2 + 1]; }
    if (QPRE){
      const float* qp = Qp + ((size_t)b * NS + t) * 1536;
      if (wv == 1){
        #pragma unroll
        for (int i = 0; i < 12; ++i) qreg[i] = qp[ln + 64 * i];
      } else if (wv == 2){
        #pragma unroll
        for (int i = 0; i < 6; ++i) qreg[i] = qp[768 + ln + 64 * i];
      } else if (wv == 3){
        #pragma unroll
        for (int i = 0; i < 6; ++i) qreg[i] = qp[1152 + ln + 64 * i];
      }
    } else {
      if (wv == 3 && t + 1 < NS){
        #pragma unroll
        for (int i = 0; i < 6; ++i) xr[i] = xin[((size_t)b * NS + t + 1) * NH + ln + 64 * i];
      }
    }

    // ---- GEMM: matvec over K=384, fp32 packed FMA + fp64 flush each 96 ----
    {
      const float* pt[D];
      #pragma unroll
      for (int d = 0; d < D; ++d) pt[d] = WTP + (size_t)d * NW + col0;
      float4 wb[D][NF4];
      #pragma unroll
      for (int d = 0; d < D; ++d){
        #pragma unroll
        for (int k = 0; k < NF4; ++k) wb[d][k] = *(const float4*)(pt[d] + 4 * k);
        pt[d] += (size_t)D * NW;
      }
      f32x2 acc[NF4 * 2];
      double accd[NF4 * 4];
      #pragma unroll
      for (int k = 0; k < NF4 * 4; ++k) accd[k] = 0.0;
      for (int c0 = 0; c0 < 384; c0 += 96){
        #pragma unroll
        for (int k = 0; k < NF4 * 2; ++k) acc[k] = f32x2{0.f, 0.f};
        for (int cc = 0; cc < 96; cc += D){
          #pragma unroll
          for (int d = 0; d < D; ++d){
            const int c = c0 + cc + d;
            f32x2 aa = ALd[grp][c][sel];
            #pragma unroll
            for (int k = 0; k < NF4; ++k){
              f32x2 w0 = f32x2{wb[d][k].x, wb[d][k].y};
              f32x2 w1 = f32x2{wb[d][k].z, wb[d][k].w};
              acc[2 * k + 0] += w0 * aa;
              acc[2 * k + 1] += w1 * aa;
            }
            #pragma unroll
            for (int k = 0; k < NF4; ++k) wb[d][k] = *(const float4*)(pt[d] + 4 * k);
            pt[d] += (size_t)D * NW;
          }
        }
        #pragma unroll
        for (int k = 0; k < NF4 * 2; ++k){
          accd[2 * k]     += (double)acc[k].x;
          accd[2 * k + 1] += (double)acc[k].y;
        }
      }
      #pragma unroll
      for (int k = 0; k < NF4; ++k){
        float4 o;
        o.x = (float)accd[4 * k + 0]; o.y = (float)accd[4 * k + 1];
        o.z = (float)accd[4 * k + 2]; o.w = (float)accd[4 * k + 3];
        *(float4*)&Zrow[grp][col0 + 4 * k] = o;
      }
    }
    __syncthreads();   // B1: Zrow ready

    // ---- NL ----
    double hn  = sc[grp][0];
    double cc2 = sc[grp][1];
    float cadj[6];
    if (wv == 0){
      // c-path
      double cn = normclip(cc2);
      float cc6[6], mv6[6]; double s_mv = 0;
      #pragma unroll
      for (int i = 0; i < 6; ++i){
        int r = ln + 64 * i;
        cc6[i] = ALd[grp][r][1].x;
        mv6[i] = Zrow[grp][1536 + r];
        s_mv += (double)mv6[i] * mv6[i];
      }
      double mvn = normclip(wredsumd(s_mv));
      double s1 = tanh(mvn / cn * artanh_(cn));
      float c1f = (float)(s1 / mvn);
      float m1[6]; double sm1 = 0;
      #pragma unroll
      for (int i = 0; i < 6; ++i){ m1[i] = c1f * mv6[i]; sm1 += (double)m1[i] * m1[i]; }
      double n1 = normclip(wredsumd(sm1));
      float l1f = (float)(artanh_(n1) / n1);
      float v6[6]; double sv = 0;
      #pragma unroll
      for (int i = 0; i < 6; ++i){ v6[i] = tanhf(l1f * m1[i]); sv += (double)v6[i] * v6[i]; }
      double nv = normclip(wredsumd(sv));
      float e1f = (float)(tanh(nv) / nv);
      float cs1[6]; double scs = 0, sccd = 0;
      #pragma unroll
      for (int i = 0; i < 6; ++i){ cs1[i] = e1f * v6[i]; scs += (double)cs1[i] * cs1[i]; sccd -= (double)cs1[i] * cc6[i]; }
      float tsf = (float)ts;
      double xnt = sqrt(fmax(384.0 * ts * ts, 1e-15));
      double swx = 0;
      #pragma unroll
      for (int i = 0; i < 6; ++i){ float w = cs1[i] * tsf; swx += (double)w * w; }
      double wxn1 = normclip(wredsumd(swx));
      double s2c = tanh(wxn1 / xnt * artanh_(xnt)) / wxn1;
      float s2f = (float)(s2c * ts);
      float cs2[6];
      #pragma unroll
      for (int i = 0; i < 6; ++i) cs2[i] = s2f * cs1[i];
      double x2a = wredsumd(scs);
      double xya = wredsumd(sccd);
      double y2a = cc2;
      double dA = fmax(1.0 + 2.0 * xya + x2a * y2a, 1e-15);
      float fXA = (float)((1.0 + 2.0 * xya + y2a) / dA);
      float fYA = (float)((1.0 - x2a) / dA);
      float A6[6]; double sA = 0, sAc = 0, sc2_ = 0;
      #pragma unroll
      for (int i = 0; i < 6; ++i){
        A6[i] = fXA * (-cs1[i]) + fYA * cc6[i];
        sA += (double)A6[i] * A6[i]; sAc += (double)A6[i] * cs2[i]; sc2_ += (double)cs2[i] * cs2[i];
      }
      double x2b = wredsumd(sA), xyb = wredsumd(sAc), y2b = wredsumd(sc2_);
      double dB = fmax(1.0 + 2.0 * xyb + x2b * y2b, 1e-15);
      float fXB = (float)((1.0 + 2.0 * xyb + y2b) / dB);
      float fYB = (float)((1.0 - x2b) / dB);
      #pragma unroll
      for (int i = 0; i < 6; ++i) cadj[i] = fXB * A6[i] + fYB * cs2[i];
    } else if (wv == 1){
      double art_hn = artanh_(hn);
      float pg[6], qg[6], out[6];
      #pragma unroll
      for (int i = 0; i < 6; ++i){
        int r = ln + 64 * i;
        pg[i] = Zrow[grp][r];
        qg[i] = QPRE ? qreg[i] : Zrow[grp][2048 + r];
      }
      gate_chain(pg, qg, hn, art_hn, xn, art_xn, out);
      #pragma unroll
      for (int i = 0; i < 6; ++i) g384[grp][0][ln + 64 * i] = out[i];
      #pragma unroll
      for (int i = 0; i < 6; ++i){
        int r = ln + 64 * i;
        pg[i] = Zrow[grp][384 + r];
        qg[i] = QPRE ? qreg[6 + i] : Zrow[grp][2048 + 384 + r];
      }
      gate_chain(pg, qg, hn, art_hn, xn, art_xn, out);
      #pragma unroll
      for (int i = 0; i < 6; ++i) g384[grp][1][ln + 64 * i] = out[i];
    } else if (wv == 2){
      double art_hn = artanh_(hn);
      float pg[6], qg[6], out[6];
      #pragma unroll
      for (int i = 0; i < 6; ++i){
        int r = ln + 64 * i;
        pg[i] = Zrow[grp][768 + r];
        qg[i] = QPRE ? qreg[i] : Zrow[grp][2048 + 768 + r];
      }
      gate_chain(pg, qg, hn, art_hn, xn, art_xn, out);
      #pragma unroll
      for (int i = 0; i < 6; ++i){
        int r = ln + 64 * i;
        g384[grp][2][r] = out[i];
        ctx[((size_t)b * NS + t) * NH + r] = out[i];   // o-gate is the context
      }
    } else {
      double art_hn = artanh_(hn);
      float pg[6], qg[6], out[6];
      #pragma unroll
      for (int i = 0; i < 6; ++i){
        int r = ln + 64 * i;
        pg[i] = Zrow[grp][1152 + r];
        qg[i] = QPRE ? qreg[i] : Zrow[grp][2048 + 1152 + r];
      }
      gate_chain(pg, qg, hn, art_hn, xn, art_xn, out);
      #pragma unroll
      for (int i = 0; i < 6; ++i) g384[grp][3][ln + 64 * i] = out[i];
    }
    __syncthreads();   // B2: gates ready

    if (wv == 0){
      // combine: cc_n = mobius_add(pw(i,ct), pw(f,c_adj)); h_n = pw(o, expmap0(tanh(cc_n)))
      float g0[6], g1[6], g2[6], g3[6];
      #pragma unroll
      for (int i = 0; i < 6; ++i){
        int r = ln + 64 * i;
        g0[i] = g384[grp][0][r]; g1[i] = g384[grp][1][r];
        g2[i] = g384[grp][2][r]; g3[i] = g384[grp][3][r];
      }
      double sct = 0, sict = 0; float wP[6];
      #pragma unroll
      for (int i = 0; i < 6; ++i){ float ct = g3[i]; sct += (double)ct * ct; wP[i] = g1[i] * ct; sict += (double)wP[i] * wP[i]; }
      double ctn = normclip(wredsumd(sct));
      double wPn = normclip(wredsumd(sict));
      float sPf = (float)(tanh(wPn / ctn * artanh_(ctn)) / wPn);
      float P6[6]; double sPP = 0;
      #pragma unroll
      for (int i = 0; i < 6; ++i){ P6[i] = sPf * wP[i]; sPP += (double)P6[i] * P6[i]; }
      double sca = 0, sfca = 0; float wQ[6];
      #pragma unroll
      for (int i = 0; i < 6; ++i){ sca += (double)cadj[i] * cadj[i]; wQ[i] = g0[i] * cadj[i]; sfca += (double)wQ[i] * wQ[i]; }
      double can = normclip(wredsumd(sca));
      double wQn = normclip(wredsumd(sfca));
      float sQf = (float)(tanh(wQn / can * artanh_(can)) / wQn);
      float Q6[6]; double sQQ = 0, sPQ = 0;
      #pragma unroll
      for (int i = 0; i < 6; ++i){ Q6[i] = sQf * wQ[i]; sQQ += (double)Q6[i] * Q6[i]; sPQ += (double)P6[i] * Q6[i]; }
      double x2c = wredsumd(sPP), y2c = wredsumd(sQQ), xyc = wredsumd(sPQ);
      double dC = fmax(1.0 + 2.0 * xyc + x2c * y2c, 1e-15);
      float fXC = (float)((1.0 + 2.0 * xyc + y2c) / dC);
      float fYC = (float)((1.0 - x2c) / dC);
      float ccn6[6], w6[6]; double sw_ = 0;
      #pragma unroll
      for (int i = 0; i < 6; ++i){ ccn6[i] = fXC * P6[i] + fYC * Q6[i]; w6[i] = tanhf(ccn6[i]); sw_ += (double)w6[i] * w6[i]; }
      double nw = normclip(wredsumd(sw_));
      float eef = (float)(tanh(nw) / nw);
      float e6[6], wH[6]; double se = 0, soe = 0;
      #pragma unroll
      for (int i = 0; i < 6; ++i){ e6[i] = eef * w6[i]; se += (double)e6[i] * e6[i]; wH[i] = g2[i] * e6[i]; soe += (double)wH[i] * wH[i]; }
      double en = normclip(wredsumd(se));
      double wHn = normclip(wredsumd(soe));
      float sHf = (float)(tanh(wHn / en * artanh_(en)) / wHn);
      float hv[6]; double sh2 = 0, scc2 = 0;
      #pragma unroll
      for (int i = 0; i < 6; ++i){
        hv[i] = sHf * wH[i];
        sh2 += (double)hv[i] * hv[i];
        scc2 += (double)ccn6[i] * ccn6[i];
      }
      double hn_next = normclip(wredsumd(sh2));
      double cc2_next = wredsumd(scc2);
      #pragma unroll
      for (int i = 0; i < 6; ++i){
        int r = ln + 64 * i;
        ALd[grp][r][0] = f32x2{hv[i], hv[i]};
        ALd[grp][r][1] = f32x2{ccn6[i], ccn6[i]};
      }
      if (ln == 0){ sc[grp][0] = hn_next; sc[grp][1] = cc2_next; }
      if (t == NS - 1){
        #pragma unroll
        for (int i = 0; i < 6; ++i) HsOut[b * NH + ln + 64 * i] = hv[i];
      }
    }
    if (!QPRE && wv == 3 && t + 1 < NS){
      #pragma unroll
      for (int i = 0; i < 6; ++i) ALd[grp][ln + 64 * i][2] = f32x2{xr[i], xr[i]};
    }
    __syncthreads();   // B3: ALd state ready for next t
  }
}

// ---------------- block reduce helpers ----------------
__device__ __forceinline__ double blocksumd(double v, double* red){
  v = wredsumd(v);
  __syncthreads();
  if ((threadIdx.x & 63) == 0) red[threadIdx.x >> 6] = v;
  __syncthreads();
  return red[0] + red[1] + red[2] + red[3];
}
__device__ __forceinline__ double blockmaxd(double v, double* red){
  #pragma unroll
  for (int off = 32; off; off >>= 1) v = fmax(v, __shfl_xor(v, off, 64));
  __syncthreads();
  if ((threadIdx.x & 63) == 0) red[threadIdx.x >> 6] = v;
  __syncthreads();
  return fmax(fmax(red[0], red[1]), fmax(red[2], red[3]));
}

// ---------------- query / scores / softmax / aw / bt ----------------
__global__ __launch_bounds__(256) void kattn1(const float* __restrict__ Hs,
    const float* __restrict__ Win, const float* __restrict__ ctx,
    const float* __restrict__ dt, const float* __restrict__ ab,
    double* __restrict__ query, double* __restrict__ aw, double* __restrict__ bt)
{
  int b = blockIdx.x; int tid = threadIdx.x;
  __shared__ double hL[NH], qL[NH], scs[NS];
  __shared__ double red[4];
  for (int r = tid; r < NH; r += 256) hL[r] = (double)Hs[b * NH + r];
  __syncthreads();
  for (int r = tid; r < NH; r += 256){
    double s = 0;
    const float* wr = Win + (size_t)r * NH;
    for (int c = 0; c < NH; ++c) s += hL[c] * (double)wr[c];
    qL[r] = s; query[b * NH + r] = s;
  }
  __syncthreads();
  int wv = tid >> 6, ln = tid & 63;
  for (int s_ = wv; s_ < NS; s_ += 4){
    const float* crow = ctx + ((size_t)b * NS + s_) * NH;
    double par = 0;
    #pragma unroll
    for (int i = 0; i < 6; ++i){ int d = ln + 64 * i; par += qL[d] * (double)crow[d]; }
    par = wredsumd(par);
    if (ln == 0) scs[s_] = par;
  }
  __syncthreads();
  double v0 = scs[tid];
  double v1 = (tid + 256 < NS) ? scs[tid + 256] : -1e300;
  double mx = blockmaxd(fmax(v0, v1), red);
  double e0 = exp(v0 - mx);
  double e1 = (tid + 256 < NS) ? exp(v1 - mx) : 0.0;
  double tot = blocksumd(e0 + e1, red);
  double a0 = e0 / tot, a1 = e1 / tot;
  double n = normclip(blocksumd(a0 * a0 + a1 * a1, red));
  double s1 = tanh(n) / n;
  double w0 = s1 * a0, w1 = s1 * a1;
  double pn = normclip(blocksumd(w0 * w0 + w1 * w1, red));
  if (pn > 0.999){ double f = 0.999 / pn; w0 *= f; w1 *= f; }
  aw[b * NS + tid] = w0;
  if (tid + 256 < NS) aw[b * NS + tid + 256] = w1;
  double abv = (double)ab[b];
  double b0 = exp(-abv * (double)dt[b * NS + tid]);
  double b1v = (tid + 256 < NS) ? exp(-abv * (double)dt[b * NS + tid + 256]) : 0.0;
  double nb = normclip(blocksumd(b0 * b0 + b1v * b1v, red));
  double sb = tanh(nb) / nb;
  double c0 = sb * b0, c1 = sb * b1v;
  double pnb = normclip(blocksumd(c0 * c0 + c1 * c1, red));
  if (pnb > 0.999){ double f = 0.999 / pnb; c0 *= f; c1 *= f; }
  bt[b * NS + tid] = c0;
  if (tid + 256 < NS) bt[b * NS + tid + 256] = c1;
}

// ---------------- hyperbolic attention mixing ----------------
__global__ __launch_bounds__(256) void kmix(const float* __restrict__ ctx,
    const double* __restrict__ aw, const double* __restrict__ bt,
    const float* __restrict__ ae, double* __restrict__ nom, double* __restrict__ den)
{
  int b = blockIdx.y; int h0 = blockIdx.x * 32;
  __shared__ float T[32][385];
  int tid = threadIdx.x;
  for (int idx = tid; idx < NS * 32; idx += 256){
    int s = idx >> 5, hh = idx & 31;
    T[hh][s] = ctx[((size_t)b * NS + s) * NH + h0 + hh];
  }
  __syncthreads();
  int wv = tid >> 6, ln = tid & 63;
  double aev = (double)ae[b];
  double aw6[6], bt6[6]; double sbt = 0;
  #pragma unroll
  for (int i = 0; i < 6; ++i){
    aw6[i] = aw[b * NS + ln + 64 * i];
    bt6[i] = bt[b * NS + ln + 64 * i];
    sbt += bt6[i] * bt6[i];
  }
  double xnb = normclip(wredsumd(sbt));
  double art_xnb = artanh_(xnb);
  double denacc = 0.0;
  for (int k = 0; k < 8; ++k){
    int hh = wv * 8 + k;
    double v[6]; double sx = 0;
    #pragma unroll
    for (int i = 0; i < 6; ++i){ v[i] = (double)T[hh][ln + 64 * i]; sx += v[i] * v[i]; }
    double xnv = normclip(wredsumd(sx));
    double wx[6]; double swx = 0;
    #pragma unroll
    for (int i = 0; i < 6; ++i){ wx[i] = aw6[i] * v[i]; swx += wx[i] * wx[i]; }
    double wxn = normclip(wredsumd(swx));
    double s1 = tanh(wxn / xnv * artanh_(xnv)) / wxn;
    double mix[6]; double sm = 0;
    #pragma unroll
    for (int i = 0; i < 6; ++i){ mix[i] = s1 * wx[i]; sm += mix[i] * mix[i]; }
    double n1 = normclip(wredsumd(sm));
    if (n1 > 0.999){ double f = 0.999 / n1;
      #pragma unroll
      for (int i = 0; i < 6; ++i) mix[i] *= f; }
    double sm2 = 0;
    #pragma unroll
    for (int i = 0; i < 6; ++i) sm2 += mix[i] * mix[i];
    double xn2 = normclip(wredsumd(sm2));
    double wx2[6]; double sw2 = 0;
    #pragma unroll
    for (int i = 0; i < 6; ++i){ wx2[i] = aev * mix[i]; sw2 += wx2[i] * wx2[i]; }
    double wxn2 = normclip(wredsumd(sw2));
    double s2 = tanh(wxn2 / xn2 * artanh_(xn2)) / wxn2;
    double tmp[6]; double st = 0;
    #pragma unroll
    for (int i = 0; i < 6; ++i){ tmp[i] = s2 * wx2[i]; st += tmp[i] * tmp[i]; }
    double n2 = normclip(wredsumd(st));
    if (n2 > 0.999){ double f = 0.999 / n2;
      #pragma unroll
      for (int i = 0; i < 6; ++i) tmp[i] *= f; }
    double wx3[6]; double sw3 = 0;
    #pragma unroll
    for (int i = 0; i < 6; ++i){ wx3[i] = tmp[i] * bt6[i]; sw3 += wx3[i] * wx3[i]; }
    double wxn3 = normclip(wredsumd(sw3));
    double s3 = tanh(wxn3 / xnb * art_xnb) / wxn3;
    double t2[6]; double st2 = 0;
    #pragma unroll
    for (int i = 0; i < 6; ++i){ t2[i] = s3 * wx3[i]; st2 += t2[i] * t2[i]; }
    double n3 = normclip(wredsumd(st2));
    if (n3 > 0.999){ double f = 0.999 / n3;
      #pragma unroll
      for (int i = 0; i < 6; ++i) t2[i] *= f; }
    #pragma unroll
    for (int i = 0; i < 6; ++i) t2[i] = fmax(t2[i], 0.0);
    double sxx = 0, syy = 0, sxy = 0;
    #pragma unroll
    for (int i = 0; i < 6; ++i){ sxx += mix[i] * mix[i]; syy += t2[i] * t2[i]; sxy += mix[i] * t2[i]; }
    sxx = wredsumd(sxx); syy = wredsumd(syy); sxy = wredsumd(sxy);
    double dn = fmax(1.0 + 2.0 * sxy + sxx * syy, 1e-15);
    double ca = (1.0 + 2.0 * sxy + syy) / dn, cb = (1.0 - sxx) / dn;
    double m2[6]; double sm3 = 0;
    #pragma unroll
    for (int i = 0; i < 6; ++i){ m2[i] = ca * mix[i] + cb * t2[i]; sm3 += m2[i] * m2[i]; }
    double n4 = normclip(wredsumd(sm3));
    if (n4 > 0.999){ double f = 0.999 / n4;
      #pragma unroll
      for (int i = 0; i < 6; ++i) m2[i] *= f; }
    double snn = 0;
    #pragma unroll
    for (int i = 0; i < 6; ++i) snn += m2[i] * m2[i];
    snn = wredsumd(snn);
    double lam = 2.0 / fmax(1.0 - snn, 1e-15);
    #pragma unroll
    for (int i = 0; i < 6; ++i) atomicAdd(&nom[b * NS + ln + 64 * i], lam * m2[i]);
    if (ln == 0) denacc += lam - 1.0;
  }
  if (ln == 0) atomicAdd(&den[b], denacc);
}

// ---------------- midpoint + logmap0 + output head ----------------
__global__ __launch_bounds__(256) void kfinal(const double* __restrict__ nom,
    const double* __restrict__ den, const double* __restrict__ query,
    const float* __restrict__ Wout, const float* __restrict__ W1,
    const float* __restrict__ b1, const float* __restrict__ W2,
    const float* __restrict__ b2, float* __restrict__ out)
{
  int b = blockIdx.x; int tid = threadIdx.x;
  __shared__ double comb[768];
  __shared__ double att[NH];
  __shared__ double x1[NH];
  __shared__ double red[4];
  double dnb = fmax(den[b], 1e-10);
  double u0 = nom[b * NS + tid] / dnb;
  double u1 = (tid + 256 < NS) ? nom[b * NS + tid + 256] / dnb : 0.0;
  double n = normclip(blocksumd(u0 * u0 + u1 * u1, red));
  double sf = tanh(0.5 * artanh_(n)) / n;
  double f0 = sf * u0, f1 = sf * u1;
  double n2 = normclip(blocksumd(f0 * f0 + f1 * f1, red));
  double sl = artanh_(n2) / n2;
  comb[tid] = sl * f0;
  if (tid + 256 < NS) comb[tid + 256] = sl * f1;
  for (int r = tid; r < NH; r += 256) comb[NH + r] = query[b * NH + r];
  __syncthreads();
  for (int r = tid; r < NH; r += 256){
    double s = 0;
    const float* wr = Wout + (size_t)r * 768;
    for (int c = 0; c < 768; ++c) s += comb[c] * (double)wr[c];
    att[r] = tanh(s);
  }
  __syncthreads();
  for (int r = tid; r < NH; r += 256){
    double s = (double)b1[r];
    const float* wr = W1 + (size_t)r * NH;
    for (int c = 0; c < NH; ++c) s += att[c] * (double)wr[c];
    x1[r] = fmax(s, 0.0);
  }
  __syncthreads();
  double p0 = 0, p1 = 0;
  for (int c = tid; c < NH; c += 256){ p0 += x1[c] * (double)W2[c]; p1 += x1[c] * (double)W2[NH + c]; }
  p0 = blocksumd(p0, red);
  p1 = blocksumd(p1, red);
  if (tid == 0){ out[b * 2 + 0] = (float)(p0 + (double)b2[0]); out[b * 2 + 1] = (float)(p1 + (double)b2[1]); }
}

extern "C" void kernel_launch(void* const* d_in, const int* in_sizes, int n_in,
                              void* d_out, int out_size, void* d_ws, size_t ws_size,
                              hipStream_t stream)
{
  (void)in_sizes; (void)n_in; (void)out_size;
  const float* inputs  = (const float*)d_in[0];
  const float* tstamps = (const float*)d_in[1];
  const float* delta_t = (const float*)d_in[2];
  const float* W_all   = (const float*)d_in[3];
  const float* U_all   = (const float*)d_in[4];
  const float* W_d     = (const float*)d_in[5];
  const float* Win     = (const float*)d_in[6];
  const float* Wout    = (const float*)d_in[7];
  const float* ae      = (const float*)d_in[8];
  const float* ab      = (const float*)d_in[9];
  const float* W1      = (const float*)d_in[10];
  const float* b1      = (const float*)d_in[11];
  const float* W2      = (const float*)d_in[12];
  const float* b2      = (const float*)d_in[13];
  float* out = (float*)d_out;

  // double region
  double* wd = (double*)d_ws;
  size_t od = 0;
  double* NOMD  = wd + od; od += (size_t)NB * NS;
  double* DEND  = wd + od; od += (size_t)NB;
  double* QUERY = wd + od; od += (size_t)NB * NH;
  double* AW    = wd + od; od += (size_t)NB * NS;
  double* BT    = wd + od; od += (size_t)NB * NS;
  double* XND   = wd + od; od += (size_t)NB * NS * 2;
  // float region
  float* wf = (float*)(wd + od);
  size_t of = 0;
  float* WTP  = wf + of; of += (size_t)392 * 4096;     // padded weights (max layout)
  float* UT   = wf + of; of += (size_t)384 * 1536;
  float* CTX  = wf + of; of += (size_t)NB * NS * NH;
  float* HS   = wf + of; of += (size_t)NB * NH;
  float* Qp   = wf + of;                               // optional 302 MB

  size_t base_bytes = od * 8 + of * 4;
  size_t q_bytes = (size_t)NB * NS * 1536 * 4;
  bool usePre = (ws_size >= base_bytes + q_bytes);
  int NW = usePre ? 2048 : 4096;

  // zero midpoint accumulators
  int nzd = NB * NS + NB;
  hipLaunchKernelGGL(kzerod, dim3((nzd + 255) / 256), dim3(256), 0, stream, NOMD, nzd);

  // weight packs + xn precompute
  int nW = 392 * NW;
  hipLaunchKernelGGL(kprepW, dim3((nW + 255) / 256), dim3(256), 0, stream,
                     W_all, W_d, U_all, WTP, NW);
  hipLaunchKernelGGL(kxn, dim3(768), dim3(256), 0, stream, inputs, XND);

  if (usePre){
    hipLaunchKernelGGL(kprepU, dim3((384 * 1536 + 255) / 256), dim3(256), 0, stream, U_all, UT);
    hipLaunchKernelGGL(kqgemm2, dim3(24, 768), dim3(256), 0, stream, inputs, UT, Qp);
    hipLaunchKernelGGL(HIP_KERNEL_NAME(krow<2048, 1>), dim3(64), dim3(512), 0, stream,
                       WTP, inputs, tstamps, XND, Qp, CTX, HS);
  } else {
    hipLaunchKernelGGL(HIP_KERNEL_NAME(krow<4096, 0>), dim3(64), dim3(512), 0, stream,
                       WTP, inputs, tstamps, XND, WTP /*unused*/, CTX, HS);
  }

  hipLaunchKernelGGL(kattn1, dim3(128), dim3(256), 0, stream,
                     HS, Win, CTX, delta_t, ab, QUERY, AW, BT);
  hipLaunchKernelGGL(kmix, dim3(12, 128), dim3(256), 0, stream, CTX, AW, BT, ae, NOMD, DEND);
  hipLaunchKernelGGL(kfinal, dim3(128), dim3(256), 0, stream,
                     NOMD, DEND, QUERY, Wout, W1, b1, W2, b2, out);
}